// Round 1
// baseline (381.246 us; speedup 1.0000x reference)
//
#include <hip/hip_runtime.h>
#include <hip/hip_bf16.h>
#include <math.h>

#define B 32
#define C 512
#define HW 3136           // 56*56
#define HW4 784           // HW / 4
#define KS 3
#define PADK 1

// ---------------------------------------------------------------------------
// Kernel 1: per-(b,c) mean over the 56x56 plane.  One block per plane.
// ---------------------------------------------------------------------------
__global__ __launch_bounds__(256) void mean_kernel(const float* __restrict__ x,
                                                   float* __restrict__ y) {
    const int plane = blockIdx.x;                       // b*C + c
    const float4* xp = (const float4*)(x + (size_t)plane * HW);
    float s = 0.f;
    for (int i = threadIdx.x; i < HW4; i += 256) {
        float4 v = xp[i];
        s += (v.x + v.y) + (v.z + v.w);
    }
    // wave (64-lane) shuffle reduction
    #pragma unroll
    for (int o = 32; o > 0; o >>= 1) s += __shfl_down(s, o, 64);
    __shared__ float red[4];
    const int wave = threadIdx.x >> 6;
    const int lane = threadIdx.x & 63;
    if (lane == 0) red[wave] = s;
    __syncthreads();
    if (threadIdx.x == 0) {
        float t = (red[0] + red[1]) + (red[2] + red[3]);
        y[plane] = t * (1.0f / (float)HW);
    }
}

// ---------------------------------------------------------------------------
// Kernel 2: deformable channel attention on y.  One block per batch.
// ---------------------------------------------------------------------------
__global__ __launch_bounds__(512) void attn_kernel(const float* __restrict__ y,
                                                   const float* __restrict__ w_offset,
                                                   const float* __restrict__ w_deform,
                                                   const float* __restrict__ b_deform,
                                                   float* __restrict__ attn) {
    const int b = blockIdx.x;
    const int p = threadIdx.x;                          // channel position 0..C-1
    __shared__ float ys[C];
    ys[p] = y[b * C + p];
    __syncthreads();

    const float ym1 = (p >= 1)     ? ys[p - 1] : 0.f;   // zero-padded conv input
    const float y0  = ys[p];
    const float yp1 = (p < C - 1)  ? ys[p + 1] : 0.f;

    float acc = b_deform[0];
    #pragma unroll
    for (int k = 0; k < KS; ++k) {
        // offset[b,k,p] = sum_j w_offset[k,0,j] * y[b, p+j-1]  (zero pad)
        const float off = w_offset[k * KS + 0] * ym1
                        + w_offset[k * KS + 1] * y0
                        + w_offset[k * KS + 2] * yp1;
        const float pos  = (float)(p + k - PADK) + off;
        const float p0f  = floorf(pos);
        const float frac = pos - p0f;
        const int   i0   = (int)p0f;
        const int   i1   = i0 + 1;
        const float v0 = (i0 >= 0 && i0 < C) ? ys[i0] : 0.f;
        const float v1 = (i1 >= 0 && i1 < C) ? ys[i1] : 0.f;
        acc += w_deform[k] * (v0 * (1.f - frac) + v1 * frac);
    }
    attn[b * C + p] = 1.f / (1.f + expf(-acc));
}

// ---------------------------------------------------------------------------
// Kernel 3: out = attn[b,c] * x.  One block per plane, float4 streams.
// ---------------------------------------------------------------------------
__global__ __launch_bounds__(256) void scale_kernel(const float* __restrict__ x,
                                                    const float* __restrict__ attn,
                                                    float* __restrict__ out) {
    const int plane = blockIdx.x;
    const float a = attn[plane];
    const float4* xp = (const float4*)(x + (size_t)plane * HW);
    float4*       op = (float4*)(out + (size_t)plane * HW);
    for (int i = threadIdx.x; i < HW4; i += 256) {
        float4 v = xp[i];
        v.x *= a; v.y *= a; v.z *= a; v.w *= a;
        op[i] = v;
    }
}

extern "C" void kernel_launch(void* const* d_in, const int* in_sizes, int n_in,
                              void* d_out, int out_size, void* d_ws, size_t ws_size,
                              hipStream_t stream) {
    const float* x        = (const float*)d_in[0];   // (32,512,56,56)
    const float* w_offset = (const float*)d_in[1];   // (3,1,3)
    const float* w_deform = (const float*)d_in[2];   // (3,)
    const float* b_deform = (const float*)d_in[3];   // scalar
    float* out  = (float*)d_out;

    float* y    = (float*)d_ws;                      // 32*512 floats
    float* attn = y + B * C;                         // 32*512 floats

    mean_kernel<<<B * C, 256, 0, stream>>>(x, y);
    attn_kernel<<<B, C, 0, stream>>>(y, w_offset, w_deform, b_deform, attn);
    scale_kernel<<<B * C, 256, 0, stream>>>(x, attn, out);
}

// Round 3
// 370.316 us; speedup vs baseline: 1.0295x; 1.0295x over previous
//
#include <hip/hip_runtime.h>
#include <hip/hip_bf16.h>
#include <math.h>

#define B 32
#define C 512
#define HW 3136           // 56*56
#define HW4 784           // HW / 4
#define KS 3
#define PADK 1

typedef float fvec4 __attribute__((ext_vector_type(4)));  // native vector: ok for nontemporal builtins

// ---------------------------------------------------------------------------
// Kernel 1: per-(b,c) mean over the 56x56 plane.  One block per plane.
// Normal (cached) loads on purpose: this pass populates L3 with x (205 MB
// fits in the 256 MB Infinity Cache) so the scale pass re-reads it from L3.
// ---------------------------------------------------------------------------
__global__ __launch_bounds__(256) void mean_kernel(const float* __restrict__ x,
                                                   float* __restrict__ y) {
    const int plane = blockIdx.x;                       // b*C + c
    const fvec4* xp = (const fvec4*)(x + (size_t)plane * HW);
    float s = 0.f;
    for (int i = threadIdx.x; i < HW4; i += 256) {
        fvec4 v = xp[i];
        s += (v.x + v.y) + (v.z + v.w);
    }
    #pragma unroll
    for (int o = 32; o > 0; o >>= 1) s += __shfl_down(s, o, 64);
    __shared__ float red[4];
    const int wave = threadIdx.x >> 6;
    const int lane = threadIdx.x & 63;
    if (lane == 0) red[wave] = s;
    __syncthreads();
    if (threadIdx.x == 0) {
        float t = (red[0] + red[1]) + (red[2] + red[3]);
        y[plane] = t * (1.0f / (float)HW);
    }
}

// ---------------------------------------------------------------------------
// Kernel 2: fused attn + scale.  One block per (b,c) plane.  Thread 0
// computes the scalar attention for this plane from y (all of y is 64 KB —
// L2-resident), broadcasts via LDS; all threads stream the plane.
// out stores are NON-TEMPORAL so they don't evict x from L3 — the x reads
// here should be L3 hits (x was just streamed by mean_kernel).
// ---------------------------------------------------------------------------
__global__ __launch_bounds__(256) void scale_attn_kernel(
        const float* __restrict__ x,
        const float* __restrict__ y,
        const float* __restrict__ w_offset,
        const float* __restrict__ w_deform,
        const float* __restrict__ b_deform,
        float* __restrict__ out) {
    const int plane = blockIdx.x;                       // b*C + c
    const int b = plane >> 9;                           // / C
    const int p = plane & (C - 1);                      // % C
    __shared__ float a_sh;

    if (threadIdx.x == 0) {
        const float* yb = y + b * C;
        const float ym1 = (p >= 1)     ? yb[p - 1] : 0.f;  // zero-padded conv input
        const float y0  = yb[p];
        const float yp1 = (p < C - 1)  ? yb[p + 1] : 0.f;

        float acc = b_deform[0];
        #pragma unroll
        for (int k = 0; k < KS; ++k) {
            const float off = w_offset[k * KS + 0] * ym1
                            + w_offset[k * KS + 1] * y0
                            + w_offset[k * KS + 2] * yp1;
            const float pos  = (float)(p + k - PADK) + off;
            const float p0f  = floorf(pos);
            const float frac = pos - p0f;
            const int   i0   = (int)p0f;
            const int   i1   = i0 + 1;
            const float v0 = (i0 >= 0 && i0 < C) ? yb[i0] : 0.f;
            const float v1 = (i1 >= 0 && i1 < C) ? yb[i1] : 0.f;
            acc += w_deform[k] * (v0 * (1.f - frac) + v1 * frac);
        }
        a_sh = 1.f / (1.f + expf(-acc));
    }
    __syncthreads();
    const float a = a_sh;

    const fvec4* xp = (const fvec4*)(x + (size_t)plane * HW);
    fvec4*       op = (fvec4*)(out + (size_t)plane * HW);
    for (int i = threadIdx.x; i < HW4; i += 256) {
        fvec4 v = xp[i];
        v *= a;
        __builtin_nontemporal_store(v, &op[i]);         // nt: don't evict x from L3
    }
}

extern "C" void kernel_launch(void* const* d_in, const int* in_sizes, int n_in,
                              void* d_out, int out_size, void* d_ws, size_t ws_size,
                              hipStream_t stream) {
    const float* x        = (const float*)d_in[0];   // (32,512,56,56)
    const float* w_offset = (const float*)d_in[1];   // (3,1,3)
    const float* w_deform = (const float*)d_in[2];   // (3,)
    const float* b_deform = (const float*)d_in[3];   // scalar
    float* out  = (float*)d_out;

    float* y = (float*)d_ws;                         // 32*512 floats

    mean_kernel<<<B * C, 256, 0, stream>>>(x, y);
    scale_attn_kernel<<<B * C, 256, 0, stream>>>(x, y, w_offset, w_deform,
                                                 b_deform, out);
}